// Round 4
// baseline (1483.254 us; speedup 1.0000x reference)
//
#include <hip/hip_runtime.h>
#include <math.h>

#define TT 10
#define BB 32
#define CIN 3
#define COUT 64
#define HH 64
#define WW 64
#define HW (HH*WW)           // 4096
#define DECAY 0.2f
#define INH 1.625f

// ---------------------------------------------------------------------------
// Tiny prep: transpose W (64,3,3,3) -> Wkc (27,64), k-major so each k-row is
// 64 consecutive floats (s_load_dwordx16-friendly, uniform across the wave).
// ---------------------------------------------------------------------------
__global__ __launch_bounds__(256) void transpose_w(
    const float* __restrict__ W, float* __restrict__ Wkc) {
    int i = blockIdx.x * 256 + threadIdx.x;
    if (i < COUT * 27) {
        int c = i / 27, k = i % 27;
        Wkc[k * COUT + c] = W[i];
    }
}

// ---------------------------------------------------------------------------
// Pass 1: per-(t,c) threshold = max over (B,H,W) of conv output. t in grid.z.
// Conv is k-outer / c-inner: 64 independent FMAs per k -> no dep-chain stall;
// weights are wave-uniform scalar loads from the k-major transpose.
// ---------------------------------------------------------------------------
__global__ __launch_bounds__(256) void thr_kernel(
    const float* __restrict__ x,        // (T,B,3,64,64)
    const float* __restrict__ Wkc,      // (27,64)
    unsigned int* __restrict__ thr_raw) // (T,64), pre-zeroed
{
    __shared__ float sx[CIN][6][66];
    __shared__ float wmax[COUT][4];

    const int tid  = threadIdx.x;
    const int wt   = tid & 63;
    const int ht   = tid >> 6;
    const int lane = tid & 63;
    const int wave = tid >> 6;
    const int h0   = blockIdx.x * 4;
    const int b    = blockIdx.y;
    const int t    = blockIdx.z;

    const float* xb = x + ((size_t)t * BB + b) * (CIN * HW);
    for (int l = tid; l < CIN * 6 * 66; l += 256) {
        int ci  = l / 396;
        int r   = (l % 396) / 66;
        int col = l % 66;
        int gh = h0 + r - 1;
        int gw = col - 1;
        float v = 0.f;
        if (gh >= 0 && gh < HH && gw >= 0 && gw < WW)
            v = xb[ci * HW + gh * WW + gw];
        sx[ci][r][col] = v;
    }
    __syncthreads();

    float xv[27];
    #pragma unroll
    for (int ci = 0; ci < CIN; ci++)
        #pragma unroll
        for (int kh = 0; kh < 3; kh++)
            #pragma unroll
            for (int kw = 0; kw < 3; kw++)
                xv[ci * 9 + kh * 3 + kw] = sx[ci][ht + kh][wt + kw];

    float acc[COUT];
    #pragma unroll
    for (int c = 0; c < COUT; c++) acc[c] = 0.f;
    #pragma unroll
    for (int k = 0; k < 27; k++) {
        float xk = xv[k];
        #pragma unroll
        for (int c = 0; c < COUT; c++)
            acc[c] = fmaf(Wkc[k * COUT + c], xk, acc[c]);  // uniform -> s_load
    }

    #pragma unroll
    for (int c = 0; c < COUT; c++) {
        float m = acc[c];
        #pragma unroll
        for (int off = 32; off > 0; off >>= 1)
            m = fmaxf(m, __shfl_xor(m, off, 64));
        if (lane == 0) wmax[c][wave] = m;
    }
    __syncthreads();

    if (tid < COUT) {
        float m = fmaxf(fmaxf(wmax[tid][0], wmax[tid][1]),
                        fmaxf(wmax[tid][2], wmax[tid][3]));
        unsigned int u = __float_as_uint(m);
        u = (u & 0x80000000u) ? ~u : (u | 0x80000000u);  // sortable encode
        atomicMax(&thr_raw[t * COUT + tid], u);
    }
}

// ---------------------------------------------------------------------------
// Pass 2: sequential T-loop, one thread per (b,h,w); mem[64] in registers.
// Conv recomputed per step with the same k-outer/c-inner structure.
// ---------------------------------------------------------------------------
__global__ __launch_bounds__(256) void lif_kernel(
    const float* __restrict__ x,              // (T,B,3,64,64)
    const float* __restrict__ Wkc,            // (27,64)
    const unsigned int* __restrict__ thr_raw, // (T,64)
    float* __restrict__ out)                  // (T,B,64,64,64)
{
    __shared__ float sx[CIN][6][66];
    __shared__ float sthr[COUT], sinv[COUT], s04[COUT], sinh_[COUT];

    const int tid = threadIdx.x;
    const int wt  = tid & 63;
    const int ht  = tid >> 6;
    const int b   = blockIdx.x >> 4;
    const int h0  = (blockIdx.x & 15) * 4;

    float mem[COUT];
    #pragma unroll
    for (int c = 0; c < COUT; c++) mem[c] = 0.f;

    #pragma unroll 1
    for (int t = 0; t < TT; t++) {
        __syncthreads();   // previous step's sx/sthr reads complete

        const float* xb = x + ((size_t)t * BB + b) * (CIN * HW);
        for (int l = tid; l < CIN * 6 * 66; l += 256) {
            int ci  = l / 396;
            int r   = (l % 396) / 66;
            int col = l % 66;
            int gh = h0 + r - 1;
            int gw = col - 1;
            float v = 0.f;
            if (gh >= 0 && gh < HH && gw >= 0 && gw < WW)
                v = xb[ci * HW + gh * WW + gw];
            sx[ci][r][col] = v;
        }
        if (tid < COUT) {
            unsigned int u = thr_raw[t * COUT + tid];
            u = (u & 0x80000000u) ? (u & 0x7FFFFFFFu) : ~u;  // decode
            float thr = __uint_as_float(u) + 1e-4f;
            sthr[tid]  = thr;
            sinv[tid]  = 8.0f / thr;
            s04[tid]   = 0.4f * thr;
            sinh_[tid] = INH * thr;
        }
        __syncthreads();

        float xv[27];
        #pragma unroll
        for (int ci = 0; ci < CIN; ci++)
            #pragma unroll
            for (int kh = 0; kh < 3; kh++)
                #pragma unroll
                for (int kw = 0; kw < 3; kw++)
                    xv[ci * 9 + kh * 3 + kw] = sx[ci][ht + kh][wt + kw];

        // conv: k-outer / c-inner, acc[64] independent FMA streams
        float acc[COUT];
        #pragma unroll
        for (int c = 0; c < COUT; c++) acc[c] = 0.f;
        #pragma unroll
        for (int k = 0; k < 27; k++) {
            float xk = xv[k];
            #pragma unroll
            for (int c = 0; c < COUT; c++)
                acc[c] = fmaf(Wkc[k * COUT + c], xk, acc[c]);  // s_load
        }

        // ASF + LIF + WTA argmax (same math/order as round 3 -> bit-identical)
        float best = -INFINITY;
        int wc = 0, sp = 0;
        #pragma unroll
        for (int c = 0; c < COUT; c++) {
            float cur = fmaxf(acc[c], 0.f);
            float z   = (cur - s04[c]) * sinv[c];
            float sig = 1.0f / (1.0f + expf(-z));
            float m   = mem[c] * DECAY + sthr[c] * sig;
            mem[c] = m;
            int   s     = m > sthr[c];
            float score = s ? m : 0.f;
            if (score > best) { best = score; wc = c; sp = s; }
        }

        float* ob = out + (((size_t)t * BB + b) * COUT) * HW + (h0 + ht) * WW + wt;
        #pragma unroll
        for (int c = 0; c < COUT; c++) {
            int fired = (c == wc) && sp;
            ob[(size_t)c * HW] = fired ? 1.f : 0.f;
            mem[c] = fired ? 0.f : (mem[c] - (sp ? sinh_[c] : 0.f));
        }
    }
}

// ---------------------------------------------------------------------------
extern "C" void kernel_launch(void* const* d_in, const int* in_sizes, int n_in,
                              void* d_out, int out_size, void* d_ws, size_t ws_size,
                              hipStream_t stream) {
    const float* x = (const float*)d_in[0];   // (T,B,3,64,64)
    const float* W = (const float*)d_in[1];   // (64,3,3,3)
    float* out     = (float*)d_out;           // (T,B,64,64,64)

    unsigned int* thr = (unsigned int*)d_ws;              // (T,64)
    float* Wkc        = (float*)((char*)d_ws + 4096);     // (27,64)

    hipMemsetAsync(thr, 0, TT * COUT * sizeof(unsigned int), stream);

    transpose_w<<<dim3(7), 256, 0, stream>>>(W, Wkc);
    thr_kernel<<<dim3(HH/4, BB, TT), 256, 0, stream>>>(x, Wkc, thr);
    lif_kernel<<<dim3(BB * HW / 256), 256, 0, stream>>>(x, Wkc, thr, out);
}